// Round 7
// baseline (108.573 us; speedup 1.0000x reference)
//
#include <hip/hip_runtime.h>

#define SEQ   8192
#define EMB   64
#define NLEAF 8192
#define KT    256           // K per LDS tile (1KB f32 per row -- long DRAM runs)
#define NT    (SEQ / KT)    // 32 tiles, full K per block

typedef __attribute__((ext_vector_type(4))) float        f32x4;
typedef __attribute__((ext_vector_type(4))) unsigned int u32x4;

// ---- bf16 RNE pack: pair (x,y) -> [bf16(x) | bf16(y)<<16] ----
__device__ __forceinline__ unsigned rne_pair(float x, float y) {
    const unsigned ux = __float_as_uint(x), uy = __float_as_uint(y);
    const unsigned rx = (ux + 0x7fffu + ((ux >> 16) & 1u)) >> 16;
    const unsigned ry = (uy + 0x7fffu + ((uy >> 16) & 1u)) & 0xffff0000u;
    return rx | ry;
}

__device__ __forceinline__ void mfma16(f32x4& d, const u32x4 a, const u32x4 b) {
    asm("v_mfma_f32_16x16x32_bf16 %0, %1, %2, %0" : "+v"(d) : "v"(a), "v"(b));
}

// Read 8 consecutive-k f32 from the swizzled 32x256 f32 A tile (1KB rows,
// 16B chunk index XORed with row&7), emit one RNE bf16 fragment.
__device__ __forceinline__ u32x4 frag_rneA(const float* buf, int row, int kk) {
    const int c = kk >> 2;          // even 16B-chunk index (0..63)
    const int s = row & 7;
    const char* base = (const char*)buf + row * 1024;
    const f32x4 v0 = *(const f32x4*)(base + 16 * (c ^ s));
    const f32x4 v1 = *(const f32x4*)(base + 16 * ((c + 1) ^ s));
    u32x4 h;
    h[0] = rne_pair(v0.x, v0.y);
    h[1] = rne_pair(v0.z, v0.w);
    h[2] = rne_pair(v1.x, v1.y);
    h[3] = rne_pair(v1.z, v1.w);
    return h;
}

// async global->LDS, 16B per lane; offset immediate ALWAYS 0 (R4 lesson).
#define GLDS16(gp, lp) \
    __builtin_amdgcn_global_load_lds( \
        (const __attribute__((address_space(1))) void*)(gp), \
        (__attribute__((address_space(3))) void*)(lp), 16, 0, 0)

// ============================================================================
// K0: W [64][8192] f32 -> bf16 RNE per-tile LDS images. Image chunk s of
// (tile t, row r) holds W[r][t*256 + 8*(s^(r&7)) .. +8]; byte addr = gid*16.
// Also zeroes the tail counter (thread 0).
// ============================================================================
__global__ __launch_bounds__(256) void k_cvtW(const float* __restrict__ W,
                                              unsigned* __restrict__ Wimg,
                                              unsigned* __restrict__ cnt)
{
    const int gid = blockIdx.x * 256 + threadIdx.x;   // 65536 = 32*64*32
    if (gid == 0)
        __hip_atomic_store(cnt, 0u, __ATOMIC_RELAXED, __HIP_MEMORY_SCOPE_AGENT);
    const int s = gid & 31;
    const int r = (gid >> 5) & 63;
    const int t = gid >> 11;
    const float* src = W + (size_t)r * SEQ + t * KT + 8 * (s ^ (r & 7));
    const f32x4 a = *(const f32x4*)(src);
    const f32x4 b = *(const f32x4*)(src + 4);
    u32x4 v;
    v[0] = rne_pair(a.x, a.y);
    v[1] = rne_pair(a.z, a.w);
    v[2] = rne_pair(b.x, b.y);
    v[3] = rne_pair(b.z, b.w);
    *(u32x4*)(Wimg + (size_t)gid * 4) = v;
}

// ============================================================================
// K1: leaf embedding GEMM, bf16 RNE MFMA, FULL K per block, bias+relu fused.
// grid 256 (1 block/CU), block 512 (8 waves), LDS 128KB.
// Wave w: 16x16 output tile at rows mr=(w&1)*16, cols nc=(w>>1)*16.
// A staged as 32 rows x 1KB contiguous runs (DRAM-activation-friendly);
// W staged from the L2-resident bf16 image. 2 buffers, 2 barriers/tile,
// counted vmcnt(8) -- never drains to 0 until the last tile.
// ============================================================================
__global__ __launch_bounds__(512, 2) void k_gemm(
        const float* __restrict__ A, const char* __restrict__ Wimg,
        const float* __restrict__ eb, float* __restrict__ h)
{
    __shared__ float sA[2][32 * 256];       // 2 x 32KB, swizzled 1KB rows
    __shared__ char  sW[2][32768];          // 2 x 32KB bf16 W tile images

    const int tid  = threadIdx.x;
    const int lane = tid & 63;
    const int wid  = tid >> 6;              // 0..7
    const int b    = blockIdx.x;
    const int gl0  = b * 32;

    // ---- A staging: wave w stages rows 4w..4w+3, one glds = one 1KB row ----
    const int ra = 4 * wid;
    const float* pA0 = A + (size_t)(gl0 + ra + 0) * SEQ + (lane ^ ((ra + 0) & 7)) * 4;
    const float* pA1 = A + (size_t)(gl0 + ra + 1) * SEQ + (lane ^ ((ra + 1) & 7)) * 4;
    const float* pA2 = A + (size_t)(gl0 + ra + 2) * SEQ + (lane ^ ((ra + 2) & 7)) * 4;
    const float* pA3 = A + (size_t)(gl0 + ra + 3) * SEQ + (lane ^ ((ra + 3) & 7)) * 4;
    // ---- W staging: wave w stages image rows 8w..8w+7 (4 x 1KB linear) ----
    const char* pW0 = Wimg + (8 * wid + 0) * 512 + lane * 16;
    const char* pW1 = Wimg + (8 * wid + 2) * 512 + lane * 16;
    const char* pW2 = Wimg + (8 * wid + 4) * 512 + lane * 16;
    const char* pW3 = Wimg + (8 * wid + 6) * 512 + lane * 16;

    const int fr = lane & 15;
    const int fq = lane >> 4;
    const int mr = (wid & 1) * 16;          // row tile
    const int nc = (wid >> 1) * 16;         // col tile
    const int wrow = nc + fr;               // W row this lane reads
    const int wswz = wrow & 7;

    f32x4 acc = {0.f, 0.f, 0.f, 0.f};

#define STAGE(bi_) do { \
    GLDS16(pA0, &sA[bi_][(ra + 0) * 256]);  pA0 += KT; \
    GLDS16(pA1, &sA[bi_][(ra + 1) * 256]);  pA1 += KT; \
    GLDS16(pA2, &sA[bi_][(ra + 2) * 256]);  pA2 += KT; \
    GLDS16(pA3, &sA[bi_][(ra + 3) * 256]);  pA3 += KT; \
    GLDS16(pW0, &sW[bi_][(8 * wid + 0) * 512]);  pW0 += 32768; \
    GLDS16(pW1, &sW[bi_][(8 * wid + 2) * 512]);  pW1 += 32768; \
    GLDS16(pW2, &sW[bi_][(8 * wid + 4) * 512]);  pW2 += 32768; \
    GLDS16(pW3, &sW[bi_][(8 * wid + 6) * 512]);  pW3 += 32768; \
} while (0)

#define COMPUTE(bi_) do { \
    const float* bufA_ = &sA[bi_][0]; \
    const char*  bufW_ = &sW[bi_][0]; \
    _Pragma("unroll") \
    for (int k32 = 0; k32 < 8; ++k32) { \
        const u32x4 af = frag_rneA(bufA_, mr + fr, k32 * 32 + fq * 8); \
        const u32x4 bf = *(const u32x4*)(bufW_ + wrow * 512 \
                                         + 16 * ((k32 * 4 + fq) ^ wswz)); \
        mfma16(acc, af, bf); \
    } \
} while (0)

    // prologue: tiles 0 and 1 (16 glds outstanding per wave)
    STAGE(0);
    STAGE(1);

    #pragma unroll 1
    for (int t = 0; t < NT; ++t) {
        if (t + 1 < NT) asm volatile("s_waitcnt vmcnt(8)" ::: "memory");
        else            asm volatile("s_waitcnt vmcnt(0)" ::: "memory");
        __builtin_amdgcn_s_barrier();
        __builtin_amdgcn_sched_barrier(0);
        COMPUTE(t & 1);
        asm volatile("s_waitcnt lgkmcnt(0)" ::: "memory");
        __builtin_amdgcn_s_barrier();
        __builtin_amdgcn_sched_barrier(0);
        if (t + 2 < NT) STAGE(t & 1);       // buf just vacated
    }

#undef STAGE
#undef COMPUTE

    // ---- epilogue: bias + relu, h[row][col] ----
    const float bias = eb[nc + fr];
    #pragma unroll
    for (int r = 0; r < 4; ++r)
        h[(size_t)(gl0 + mr + fq * 4 + r) * EMB + nc + fr] =
            fmaxf(acc[r] + bias, 0.0f);
}

// ============================================================================
// Tree helpers (fp32 exact). Lane = output dim e; activations broadcast.
// Weights as WtV[j][e] f32x4: wave-contiguous ds_read_b128, conflict-free.
// ============================================================================
__device__ __forceinline__ void load_WtV(f32x4 (*WtV)[64],
                                         const float* __restrict__ WW, int tid) {
    const int e  = tid & 63;
    const int jg = tid >> 6;
    #pragma unroll
    for (int u = 0; u < 8; ++u) {
        const int j = jg * 8 + u;
        WtV[j][e] = *(const f32x4*)&WW[e * 128 + 4 * j];
    }
}

__device__ __forceinline__ float hsum4(const f32x4 a) {
    return a.x + a.y + a.z + a.w;
}

__device__ __forceinline__ float* tree_levels(float* bufA, float* bufB,
        const f32x4 (*WtV)[64], float wb, int n0, int nlv, int tid)
{
    const int lane = tid & 63;
    const int wid  = tid >> 6;
    float* src = bufA;
    float* dst = bufB;
    int n = n0;
    for (int lvl = 0; lvl < nlv; ++lvl) {
        const int nodes = n >> 1;
        for (int base = wid * 4; base < nodes; base += 16) {
            const int cnt = (nodes - base < 4) ? (nodes - base) : 4;
            if (cnt == 4) {
                f32x4 ac0 = {0.f,0.f,0.f,0.f}, ac1 = ac0, ac2 = ac0, ac3 = ac0;
                const float* x0 = src + (2 * (base + 0)) * 68;
                const float* x1 = src + (2 * (base + 1)) * 68;
                const float* x2 = src + (2 * (base + 2)) * 68;
                const float* x3 = src + (2 * (base + 3)) * 68;
                #pragma unroll
                for (int j = 0; j < 32; ++j) {
                    const f32x4 w4 = WtV[j][lane];
                    const int off = (j < 16) ? (4 * j) : (68 + 4 * (j - 16));
                    ac0 += w4 * *(const f32x4*)(x0 + off);
                    ac1 += w4 * *(const f32x4*)(x1 + off);
                    ac2 += w4 * *(const f32x4*)(x2 + off);
                    ac3 += w4 * *(const f32x4*)(x3 + off);
                }
                dst[(base + 0) * 68 + lane] = fmaxf(wb + hsum4(ac0), 0.f);
                dst[(base + 1) * 68 + lane] = fmaxf(wb + hsum4(ac1), 0.f);
                dst[(base + 2) * 68 + lane] = fmaxf(wb + hsum4(ac2), 0.f);
                dst[(base + 3) * 68 + lane] = fmaxf(wb + hsum4(ac3), 0.f);
            } else {
                for (int u = 0; u < cnt; ++u) {
                    f32x4 ac = {0.f, 0.f, 0.f, 0.f};
                    const float* x = src + (2 * (base + u)) * 68;
                    #pragma unroll
                    for (int j = 0; j < 32; ++j) {
                        const f32x4 w4 = WtV[j][lane];
                        const int off = (j < 16) ? (4 * j) : (68 + 4 * (j - 16));
                        ac += w4 * *(const f32x4*)(x + off);
                    }
                    dst[(base + u) * 68 + lane] = fmaxf(wb + hsum4(ac), 0.f);
                }
            }
        }
        __syncthreads();
        float* tswp = src; src = dst; dst = tswp;
        n = nodes;
    }
    return src;   // root row after final swap
}

// K2: tree levels 1..5 (32 leaves -> 1 root per block). grid 256.
// h already has bias+relu applied.
__global__ __launch_bounds__(256) void k_tree32(const float* __restrict__ h,
        const float* __restrict__ WW, const float* __restrict__ Wb,
        float* __restrict__ roots)
{
    __shared__ float hA[32][68];
    __shared__ float hB[16][68];
    __shared__ f32x4 WtV[32][64];
    const int tid = threadIdx.x;
    const int b   = blockIdx.x;
    load_WtV(WtV, WW, tid);
    {
        const int lf = tid >> 3;
        const int e0 = (tid & 7) * 8;
        const size_t base = (size_t)(b * 32 + lf) * EMB + e0;
        *(f32x4*)&hA[lf][e0]     = *(const f32x4*)&h[base];
        *(f32x4*)&hA[lf][e0 + 4] = *(const f32x4*)&h[base + 4];
    }
    const float wb = Wb[tid & 63];
    __syncthreads();
    float* root = tree_levels(&hA[0][0], &hB[0][0], WtV, wb, 32, 5, tid);
    if (tid < 64) roots[b * 64 + tid] = root[tid];
}

// K3: fused tail. grid 16: each block does levels 6..9 (16 roots -> 1);
// the LAST block also does levels 10..13 + projection (G16 fencing).
__global__ __launch_bounds__(256) void k_tail(const float* __restrict__ in,
        const float* __restrict__ WW, const float* __restrict__ Wb,
        const float* __restrict__ pW, const float* __restrict__ pb,
        float* __restrict__ l9, unsigned* __restrict__ cnt,
        float* __restrict__ out)
{
    __shared__ float hA[32][68];
    __shared__ float hB[16][68];
    __shared__ f32x4 WtV[32][64];
    __shared__ int sflag;
    const int tid = threadIdx.x;
    load_WtV(WtV, WW, tid);
    {
        const int r  = tid >> 4;
        const int e0 = (tid & 15) * 4;
        *(f32x4*)&hA[r][e0] =
            *(const f32x4*)&in[(size_t)(blockIdx.x * 16 + r) * EMB + e0];
    }
    const float wb = Wb[tid & 63];
    __syncthreads();
    float* root = tree_levels(&hA[0][0], &hB[0][0], WtV, wb, 16, 4, tid);
    if (tid < 64)
        __hip_atomic_store(&l9[blockIdx.x * 64 + tid], root[tid],
                           __ATOMIC_RELAXED, __HIP_MEMORY_SCOPE_AGENT);
    __threadfence();
    if (tid == 0)
        sflag = (__hip_atomic_fetch_add(cnt, 1u, __ATOMIC_ACQ_REL,
                                        __HIP_MEMORY_SCOPE_AGENT) == 15u);
    __syncthreads();
    if (!sflag) return;

    __builtin_amdgcn_fence(__ATOMIC_ACQUIRE, "agent");
    {
        const int r  = tid >> 4;
        const int e0 = (tid & 15) * 4;
        f32x4 v;
        v.x = __hip_atomic_load(&l9[r * 64 + e0 + 0], __ATOMIC_RELAXED, __HIP_MEMORY_SCOPE_AGENT);
        v.y = __hip_atomic_load(&l9[r * 64 + e0 + 1], __ATOMIC_RELAXED, __HIP_MEMORY_SCOPE_AGENT);
        v.z = __hip_atomic_load(&l9[r * 64 + e0 + 2], __ATOMIC_RELAXED, __HIP_MEMORY_SCOPE_AGENT);
        v.w = __hip_atomic_load(&l9[r * 64 + e0 + 3], __ATOMIC_RELAXED, __HIP_MEMORY_SCOPE_AGENT);
        *(f32x4*)&hA[r][e0] = v;
    }
    __syncthreads();
    root = tree_levels(&hA[0][0], &hB[0][0], WtV, wb, 16, 4, tid);
    if (tid < 64) {
        const float hv = root[tid];
        float t0 = hv * pW[tid];
        float t1 = hv * pW[64 + tid];
        #pragma unroll
        for (int off = 32; off > 0; off >>= 1) {
            t0 += __shfl_down(t0, off);
            t1 += __shfl_down(t1, off);
        }
        if (tid == 0) { out[0] = t0 + pb[0]; out[1] = t1 + pb[1]; }
    }
}

extern "C" void kernel_launch(void* const* d_in, const int* in_sizes, int n_in,
                              void* d_out, int out_size, void* d_ws, size_t ws_size,
                              hipStream_t stream)
{
    const float* A  = (const float*)d_in[0];   // leaf_seqs [8192][8192]
    const float* eW = (const float*)d_in[1];   // emb_W     [64][8192]
    const float* eb = (const float*)d_in[2];   // emb_b     [64]
    const float* WW = (const float*)d_in[3];   // W_W       [64][128]
    const float* Wb = (const float*)d_in[4];   // W_b       [64]
    const float* pW = (const float*)d_in[5];   // proj_W    [2][64]
    const float* pb = (const float*)d_in[6];   // proj_b    [2]
    float* out = (float*)d_out;

    float*    h     = (float*)d_ws;                    // [8192][64] f32 = 2MB
    float*    roots = h + (size_t)NLEAF * EMB;         // [256][64]
    float*    l9    = roots + 256 * EMB;               // [16][64]
    unsigned* cnt   = (unsigned*)(l9 + 16 * EMB);
    char*     Wimg  = (char*)d_ws + (size_t)4 * 1024 * 1024;  // 1MB bf16 imgs

    k_cvtW  <<<dim3(256), dim3(256), 0, stream>>>(eW, (unsigned*)Wimg, cnt);
    k_gemm  <<<dim3(256), dim3(512), 0, stream>>>(A, Wimg, eb, h);
    k_tree32<<<dim3(256), dim3(256), 0, stream>>>(h, WW, Wb, roots);
    k_tail  <<<dim3(16),  dim3(256), 0, stream>>>(roots, WW, Wb, pW, pb,
                                                  l9, cnt, out);
}